// Round 12
// baseline (601.925 us; speedup 1.0000x reference)
//
#include <hip/hip_runtime.h>

#define NBATCH 2048

typedef __attribute__((ext_vector_type(8))) short short8;
typedef __attribute__((ext_vector_type(4))) short short4v;
typedef __attribute__((ext_vector_type(4))) float f32x4;
typedef __attribute__((ext_vector_type(4))) unsigned short us4;

__device__ __forceinline__ unsigned short f2bf(float f) {
    unsigned int u = __float_as_uint(f);
    u += 0x7FFFu + ((u >> 16) & 1u);
    return (unsigned short)(u >> 16);
}

__device__ __forceinline__ short4v pack4(f32x4 v) {
    short4v r;
    r[0] = (short)f2bf(v[0]); r[1] = (short)f2bf(v[1]);
    r[2] = (short)f2bf(v[2]); r[3] = (short)f2bf(v[3]);
    return r;
}
__device__ __forceinline__ short8 pack8(f32x4 lo, f32x4 hi) {
    short8 r;
    r[0] = (short)f2bf(lo[0]); r[1] = (short)f2bf(lo[1]);
    r[2] = (short)f2bf(lo[2]); r[3] = (short)f2bf(lo[3]);
    r[4] = (short)f2bf(hi[0]); r[5] = (short)f2bf(hi[1]);
    r[6] = (short)f2bf(hi[2]); r[7] = (short)f2bf(hi[3]);
    return r;
}

__device__ __forceinline__ f32x4 mfma16(short4v a, short4v b, f32x4 c) {
#if __has_builtin(__builtin_amdgcn_mfma_f32_16x16x16bf16_1k)
    return __builtin_amdgcn_mfma_f32_16x16x16bf16_1k(a, b, c, 0, 0, 0);
#elif __has_builtin(__builtin_amdgcn_mfma_f32_16x16x16_bf16)
    return __builtin_amdgcn_mfma_f32_16x16x16_bf16(a, b, c, 0, 0, 0);
#else
    asm volatile("v_mfma_f32_16x16x16_bf16 %0, %1, %2, %0" : "+v"(c) : "v"(a), "v"(b));
    return c;
#endif
}
#define MFMA32(a, b, c) __builtin_amdgcn_mfma_f32_16x16x32_bf16(a, b, c, 0, 0, 0)

#define SW(t) ((((t) ^ ((t) >> 3)) & 7) << 4)

// ws layout (bytes)
#define IW_OFF    0u        // I64 bf16 [64][64] (unused by kernel now; layout kept)
#define PMW_OFF   8192u     // (pm_w + I) bf16 [4][64][64]
#define THW_OFF   40960u    // [256][512] bf16
#define PHW_OFF   303104u   // [256][512] bf16
#define GW_OFF    565248u   // [256][512] bf16
#define OUTW_OFF  827392u   // [512][256] bf16 (BN-scaled)
#define OUTB_OFF  1089536u  // [512] f32 (folded BN bias)
#define WS_BYTES  1091584u

__global__ void prep_kernel(const float* __restrict__ pm_w, const float* __restrict__ g_w,
                            const float* __restrict__ th_w, const float* __restrict__ ph_w,
                            const float* __restrict__ out_w, const float* __restrict__ gamma,
                            const float* __restrict__ beta, const float* __restrict__ mean,
                            const float* __restrict__ var, char* __restrict__ ws) {
    int i = blockIdx.x * 256 + threadIdx.x;
    unsigned short* iw  = (unsigned short*)(ws + IW_OFF);
    unsigned short* pmw = (unsigned short*)(ws + PMW_OFF);
    unsigned short* thw = (unsigned short*)(ws + THW_OFF);
    unsigned short* phw = (unsigned short*)(ws + PHW_OFF);
    unsigned short* gww = (unsigned short*)(ws + GW_OFF);
    unsigned short* oww = (unsigned short*)(ws + OUTW_OFF);
    float* ob = (float*)(ws + OUTB_OFF);
    if (i < 4096) iw[i] = f2bf(((i >> 6) == (i & 63)) ? 1.0f : 0.0f);
    if (i < 16384) {
        float ident = (((i >> 6) & 63) == (i & 63)) ? 1.0f : 0.0f;
        pmw[i] = f2bf(pm_w[i] + ident);
    }
    if (i < 131072) {
        thw[i] = f2bf(th_w[i]);
        phw[i] = f2bf(ph_w[i]);
        gww[i] = f2bf(g_w[i]);
        int o = i >> 8;
        float inv = gamma[o] * rsqrtf(var[o] + 1e-5f);
        oww[i] = f2bf(out_w[i] * inv);
    }
    if (i < 512) {
        float inv = gamma[i] * rsqrtf(var[i] + 1e-5f);
        ob[i] = beta[i] - mean[i] * inv;
    }
}

// One batch per block, 4 waves, wave = HEAD. launch_bounds(256,2): 2
// independent blocks/CU at a 256-reg cap (R9-verified spill-free, 389us).
// R12: T0 (q^T staging) and T1 (Theta phase) DELETED — Theta is computed
// straight from global q via the R6-verified identity-MFMA transpose
// (D[c][t]=q*I chains into Theta's mfma16 B-operand), interleaved with the
// ctx' staging inside ONE merged phase. 6 phases -> 4, 5 barriers -> 3;
// the q-transpose chains fill the shadow of ctx's HBM latency.
// LDS 64KB: ctx' frag-array -> Y^T (32KB). rule #20: all subscripts static.
__global__ __launch_bounds__(256, 2)
void lawin_main(const float* __restrict__ query, const float* __restrict__ context,
                const float* __restrict__ pm_b, const float* __restrict__ th_b,
                const float* __restrict__ ph_b, const float* __restrict__ g_b,
                const char* __restrict__ ws, float* __restrict__ out) {
    __shared__ __align__(16) char FR[65536];

    const char* pmw = ws + PMW_OFF;
    const char* thw = ws + THW_OFF;
    const char* phw = ws + PHW_OFF;
    const char* gww = ws + GW_OFF;
    const char* oww = ws + OUTW_OFF;
    const float* ob = (const float*)(ws + OUTB_OFF);

    const int b = blockIdx.x;
    const int tid = threadIdx.x;
    const int wid = tid >> 6;          // wave = head
    const int lane = tid & 63;
    const int l15 = lane & 15;
    const int l4 = lane >> 4;
    const int h = wid;

    const float* qb = query + (size_t)b * 32768;
    const float* cbp = context + (size_t)b * 32768;
    float* outb = out + (size_t)b * 32768;

    // ---------- MERGED PHASE: ctx' staging + Theta (from global q, no LDS) ----------
    short4v thB[4][4];   // Theta as S-mfma B-frags [d16-tile][nq16-tile]
    {
        short4v idf;     // per-lane identity B-frag I[t][t']
        #pragma unroll
        for (int i = 0; i < 4; ++i) idf[i] = (short)((l4 * 4 + i == l15) ? 0x3F80 : 0);
        const f32x4 fzero = {0.f, 0.f, 0.f, 0.f};

        f32x4 acc[4][4] = {};   // Theta acc [d-tile][nq-tile]

        // one Theta k16-chunk: transpose q tile via identity MFMA, accumulate
        auto theta_ks = [&](int ks) {
            short4v qtB[4];
            #pragma unroll
            for (int tt = 0; tt < 4; ++tt) {
                f32x4 qv = *(const f32x4*)(qb + (ks * 16 + l15) * 64 + tt * 16 + l4 * 4);
                qtB[tt] = pack4(mfma16(pack4(qv), idf, fzero));
            }
            #pragma unroll
            for (int td = 0; td < 4; ++td) {
                short4v aw = *(const short4v*)(thw + (h * 64 + td * 16 + l15) * 1024 + ks * 32 + l4 * 8);
                #pragma unroll
                for (int tt = 0; tt < 4; ++tt)
                    acc[td][tt] = mfma16(aw, qtB[tt], acc[td][tt]);
            }
        };

        f32x4 bst[16];   // batched ctx loads (issued up-front, R11-proven form)
        auto gload = [&](int cw) {
            #pragma unroll
            for (int k2 = 0; k2 < 2; ++k2)
                #pragma unroll
                for (int ct = 0; ct < 4; ++ct) {
                    const float* p = cbp + (cw * 64 + ct * 16 + l15) * 64 + k2 * 32 + l4 * 8;
                    bst[k2 * 8 + ct * 2]     = *(const f32x4*)p;
                    bst[k2 * 8 + ct * 2 + 1] = *(const f32x4*)(p + 4);
                }
        };
        auto comp = [&](int cw) {
            const char* Bm = pmw + h * 8192;
            const float* bias = pm_b + h * 64;
            short8 pa[8];
            #pragma unroll
            for (int k2 = 0; k2 < 2; ++k2)
                #pragma unroll
                for (int ct = 0; ct < 4; ++ct)
                    pa[k2 * 4 + ct] = pack8(bst[k2 * 8 + ct * 2], bst[k2 * 8 + ct * 2 + 1]);
            #pragma unroll
            for (int mth = 0; mth < 2; ++mth) {
                f32x4 sacc[4][2] = {};
                #pragma unroll
                for (int k2 = 0; k2 < 2; ++k2) {
                    short8 bb[2];
                    #pragma unroll
                    for (int mt2 = 0; mt2 < 2; ++mt2)
                        bb[mt2] = *(const short8*)(Bm + (mth * 32 + mt2 * 16 + l15) * 128 + k2 * 64 + l4 * 16);
                    #pragma unroll
                    for (int ct = 0; ct < 4; ++ct)
                        #pragma unroll
                        for (int mt2 = 0; mt2 < 2; ++mt2)
                            sacc[ct][mt2] = MFMA32(pa[k2 * 4 + ct], bb[mt2], sacc[ct][mt2]);
                }
                #pragma unroll
                for (int ct = 0; ct < 4; ++ct)
                    #pragma unroll
                    for (int mt2 = 0; mt2 < 2; ++mt2) {
                        f32x4 v = sacc[ct][mt2] + bias[mth * 32 + mt2 * 16 + l15];
                        us4 pk;
                        pk[0] = f2bf(v[0]); pk[1] = f2bf(v[1]); pk[2] = f2bf(v[2]); pk[3] = f2bf(v[3]);
                        const int c32 = cw * 2 + (ct >> 1);
                        const int mt = mth * 2 + mt2;
                        const int lanep = ((ct & 1) * 2 + (l4 >> 1)) * 16 + l15;
                        *(us4*)(FR + (c32 * 4 + mt) * 1024 + lanep * 16 + (l4 & 1) * 8) = pk;
                    }
            }
        };

        gload(wid * 2);                    // ctx group 0 loads in flight
        #pragma unroll
        for (int ks = 0; ks < 8; ++ks) theta_ks(ks);     // q chains under them
        comp(wid * 2);
        gload(wid * 2 + 1);                // ctx group 1 loads in flight
        #pragma unroll
        for (int ks = 8; ks < 16; ++ks) theta_ks(ks);
        comp(wid * 2 + 1);
        #pragma unroll
        for (int ks = 16; ks < 32; ++ks) theta_ks(ks);   // remaining Theta K

        #pragma unroll
        for (int td = 0; td < 4; ++td) {
            f32x4 bv = *(const f32x4*)(th_b + h * 64 + td * 16 + l4 * 4);
            #pragma unroll
            for (int tt = 0; tt < 4; ++tt)
                thB[td][tt] = pack4(acc[td][tt] + bv);
        }
    }
    __syncthreads();   // ctx' frag-array complete

    // ---------- T3: Phi -> S^T -> softmax -> pB ----------
    short4v pB[4][4];    // [nc16-tile][nq16-tile] PV A-frags
    {
        f32x4 s_acc[4][4] = {};   // S^T tiles: row=nc(l4*4+r), col=nq(l15)
        #pragma unroll
        for (int dh = 0; dh < 2; ++dh) {          // FULL unroll: indexes thB
            f32x4 pacc[2][4] = {};   // Phi D[d][nc]: [td2][tc]
            #pragma unroll 2
            for (int ks = 0; ks < 16; ++ks) {
                short8 a[2], bb[4];
                #pragma unroll
                for (int td2 = 0; td2 < 2; ++td2)
                    a[td2] = *(const short8*)(phw + (h * 64 + dh * 32 + td2 * 16 + l15) * 1024 + ks * 64 + l4 * 16);
                #pragma unroll
                for (int tc = 0; tc < 4; ++tc)
                    bb[tc] = *(const short8*)(FR + (ks * 4 + tc) * 1024 + lane * 16);
                #pragma unroll
                for (int td2 = 0; td2 < 2; ++td2)
                    #pragma unroll
                    for (int tc = 0; tc < 4; ++tc)
                        pacc[td2][tc] = MFMA32(a[td2], bb[tc], pacc[td2][tc]);
            }
            #pragma unroll
            for (int td2 = 0; td2 < 2; ++td2) {
                f32x4 bv = *(const f32x4*)(ph_b + h * 64 + dh * 32 + td2 * 16 + l4 * 4);
                #pragma unroll
                for (int tc = 0; tc < 4; ++tc) {
                    short4v phB = pack4(pacc[td2][tc] + bv);
                    #pragma unroll
                    for (int tb = 0; tb < 4; ++tb)
                        s_acc[tc][tb] = mfma16(phB, thB[dh * 2 + td2][tb], s_acc[tc][tb]);
                }
            }
        }
        // softmax over nc (per-lane 16 values + shfl over l4), scale 1/8
        #pragma unroll
        for (int tb = 0; tb < 4; ++tb) {
            float mx = -1e30f;
            #pragma unroll
            for (int tc = 0; tc < 4; ++tc)
                #pragma unroll
                for (int r = 0; r < 4; ++r) mx = fmaxf(mx, s_acc[tc][tb][r]);
            mx = fmaxf(mx, __shfl_xor(mx, 16));
            mx = fmaxf(mx, __shfl_xor(mx, 32));
            float sum = 0.f;
            #pragma unroll
            for (int tc = 0; tc < 4; ++tc)
                #pragma unroll
                for (int r = 0; r < 4; ++r) {
                    float v = __expf((s_acc[tc][tb][r] - mx) * 0.125f);
                    s_acc[tc][tb][r] = v;
                    sum += v;
                }
            sum += __shfl_xor(sum, 16);
            sum += __shfl_xor(sum, 32);
            float rinv = 1.0f / sum;
            #pragma unroll
            for (int tc = 0; tc < 4; ++tc)
                pB[tc][tb] = pack4(s_acc[tc][tb] * rinv);
        }
    }

    // ---------- T4: G^T and PV chain -> y_acc ----------
    f32x4 y_acc[4][4] = {};    // [nq-tile][dg16-tile(local)], row=nq, col=dg
    #pragma unroll
    for (int gh = 0; gh < 2; ++gh) {              // FULL unroll: indexes y_acc
        f32x4 gacc[4][2] = {};   // G D[nc][dg]: [tn][tg]
        #pragma unroll 2
        for (int ks = 0; ks < 16; ++ks) {
            short8 a[4], bb[2];
            #pragma unroll
            for (int tn = 0; tn < 4; ++tn)
                a[tn] = *(const short8*)(FR + (ks * 4 + tn) * 1024 + lane * 16);
            #pragma unroll
            for (int tg = 0; tg < 2; ++tg)
                bb[tg] = *(const short8*)(gww + (h * 64 + gh * 32 + tg * 16 + l15) * 1024 + ks * 64 + l4 * 16);
            #pragma unroll
            for (int tn = 0; tn < 4; ++tn)
                #pragma unroll
                for (int tg = 0; tg < 2; ++tg)
                    gacc[tn][tg] = MFMA32(a[tn], bb[tg], gacc[tn][tg]);
        }
        #pragma unroll
        for (int tg = 0; tg < 2; ++tg) {
            float gbv = g_b[h * 64 + gh * 32 + tg * 16 + l15];
            #pragma unroll
            for (int tn = 0; tn < 4; ++tn) {
                short4v gB = pack4(gacc[tn][tg] + gbv);
                #pragma unroll
                for (int tb = 0; tb < 4; ++tb)
                    y_acc[tb][gh * 2 + tg] = mfma16(pB[tn][tb], gB, y_acc[tb][gh * 2 + tg]);
            }
        }
    }
    __syncthreads();   // all waves done reading ctx' frags

    // ---------- Y^T bf16 [64][256] (SW-swizzled) -> FR[0:32K) ----------
    #pragma unroll
    for (int tb = 0; tb < 4; ++tb)
        #pragma unroll
        for (int tdg = 0; tdg < 4; ++tdg)
            #pragma unroll
            for (int r = 0; r < 4; ++r) {
                int nq = tb * 16 + l4 * 4 + r;
                int dg = h * 64 + tdg * 16 + l15;
                *(unsigned short*)(FR + nq * 512 + ((2 * dg) ^ SW(nq))) = f2bf(y_acc[tb][tdg][r]);
            }
    __syncthreads();

    // ---------- T5: out-proj (BN folded) + bias + f32 query residual ----------
    #pragma unroll 1
    for (int och = 0; och < 4; ++och) {    // och only feeds addresses; acc local per iter
        const int ob0 = wid * 128 + och * 32;
        f32x4 acc[4][2] = {};
        #pragma unroll 2
        for (int ks = 0; ks < 8; ++ks) {
            const int kb = ks * 64 + l4 * 16;
            short8 a[4], bb[2];
            #pragma unroll
            for (int tr = 0; tr < 4; ++tr) {
                int tok = tr * 16 + l15;
                a[tr] = *(const short8*)(FR + tok * 512 + (kb ^ SW(tok)));
            }
            #pragma unroll
            for (int oc = 0; oc < 2; ++oc)
                bb[oc] = *(const short8*)(oww + (ob0 + oc * 16 + l15) * 512 + kb);
            #pragma unroll
            for (int tr = 0; tr < 4; ++tr)
                #pragma unroll
                for (int oc = 0; oc < 2; ++oc)
                    acc[tr][oc] = MFMA32(a[tr], bb[oc], acc[tr][oc]);
        }
        #pragma unroll
        for (int oc = 0; oc < 2; ++oc) {
            const int o = ob0 + oc * 16 + l15;
            const float bias = ob[o];
            #pragma unroll
            for (int tr = 0; tr < 4; ++tr) {
                const int tt = tr * 16 + l4 * 4;
                f32x4 qv = *(const f32x4*)(qb + o * 64 + tt);
                f32x4 ov;
                #pragma unroll
                for (int r = 0; r < 4; ++r) ov[r] = acc[tr][oc][r] + bias + qv[r];
                *(f32x4*)(outb + o * 64 + tt) = ov;
            }
        }
    }
}

extern "C" void kernel_launch(void* const* d_in, const int* in_sizes, int n_in,
                              void* d_out, int out_size, void* d_ws, size_t ws_size,
                              hipStream_t stream) {
    const float* query   = (const float*)d_in[0];
    const float* context = (const float*)d_in[1];
    const float* pm_w    = (const float*)d_in[2];
    const float* pm_b    = (const float*)d_in[3];
    const float* g_w     = (const float*)d_in[4];
    const float* g_b     = (const float*)d_in[5];
    const float* th_w    = (const float*)d_in[6];
    const float* th_b    = (const float*)d_in[7];
    const float* ph_w    = (const float*)d_in[8];
    const float* ph_b    = (const float*)d_in[9];
    const float* out_w   = (const float*)d_in[10];
    const float* gamma   = (const float*)d_in[11];
    const float* beta    = (const float*)d_in[12];
    const float* mean    = (const float*)d_in[13];
    const float* var     = (const float*)d_in[14];
    char* ws = (char*)d_ws;
    float* out = (float*)d_out;

    if (ws_size < WS_BYTES) return;

    prep_kernel<<<512, 256, 0, stream>>>(pm_w, g_w, th_w, ph_w, out_w, gamma, beta, mean, var, ws);
    lawin_main<<<NBATCH, 256, 0, stream>>>(query, context, pm_b, th_b, ph_b, g_b, ws, out);
}

// Round 14
// 584.928 us; speedup vs baseline: 1.0291x; 1.0291x over previous
//
#include <hip/hip_runtime.h>

#define NBATCH 2048

typedef __attribute__((ext_vector_type(8))) short short8;
typedef __attribute__((ext_vector_type(4))) short short4v;
typedef __attribute__((ext_vector_type(4))) float f32x4;
typedef __attribute__((ext_vector_type(4))) unsigned short us4;

__device__ __forceinline__ unsigned short f2bf(float f) {
    unsigned int u = __float_as_uint(f);
    u += 0x7FFFu + ((u >> 16) & 1u);
    return (unsigned short)(u >> 16);
}
__device__ __forceinline__ float bf2f(unsigned short h) {
    return __uint_as_float(((unsigned int)h) << 16);
}

__device__ __forceinline__ short4v pack4(f32x4 v) {
    short4v r;
    r[0] = (short)f2bf(v[0]); r[1] = (short)f2bf(v[1]);
    r[2] = (short)f2bf(v[2]); r[3] = (short)f2bf(v[3]);
    return r;
}
__device__ __forceinline__ short8 pack8(f32x4 lo, f32x4 hi) {
    short8 r;
    r[0] = (short)f2bf(lo[0]); r[1] = (short)f2bf(lo[1]);
    r[2] = (short)f2bf(lo[2]); r[3] = (short)f2bf(lo[3]);
    r[4] = (short)f2bf(hi[0]); r[5] = (short)f2bf(hi[1]);
    r[6] = (short)f2bf(hi[2]); r[7] = (short)f2bf(hi[3]);
    return r;
}

__device__ __forceinline__ f32x4 mfma16(short4v a, short4v b, f32x4 c) {
#if __has_builtin(__builtin_amdgcn_mfma_f32_16x16x16bf16_1k)
    return __builtin_amdgcn_mfma_f32_16x16x16bf16_1k(a, b, c, 0, 0, 0);
#elif __has_builtin(__builtin_amdgcn_mfma_f32_16x16x16_bf16)
    return __builtin_amdgcn_mfma_f32_16x16x16_bf16(a, b, c, 0, 0, 0);
#else
    asm volatile("v_mfma_f32_16x16x16_bf16 %0, %1, %2, %0" : "+v"(c) : "v"(a), "v"(b));
    return c;
#endif
}
#define MFMA32(a, b, c) __builtin_amdgcn_mfma_f32_16x16x32_bf16(a, b, c, 0, 0, 0)

#define SW(t) ((((t) ^ ((t) >> 3)) & 7) << 4)

// ws layout (bytes)
#define IW_OFF    0u        // I64 bf16 [64][64]
#define PMW_OFF   8192u     // (pm_w + I) bf16 [4][64][64]
#define THW_OFF   40960u    // [256][512] bf16
#define PHW_OFF   303104u   // [256][512] bf16
#define GW_OFF    565248u   // [256][512] bf16
#define OUTW_OFF  827392u   // [512][256] bf16 (BN-scaled)
#define OUTB_OFF  1089536u  // [512] f32 (folded BN bias)
#define WS_BYTES  1091584u

__global__ void prep_kernel(const float* __restrict__ pm_w, const float* __restrict__ g_w,
                            const float* __restrict__ th_w, const float* __restrict__ ph_w,
                            const float* __restrict__ out_w, const float* __restrict__ gamma,
                            const float* __restrict__ beta, const float* __restrict__ mean,
                            const float* __restrict__ var, char* __restrict__ ws) {
    int i = blockIdx.x * 256 + threadIdx.x;
    unsigned short* iw  = (unsigned short*)(ws + IW_OFF);
    unsigned short* pmw = (unsigned short*)(ws + PMW_OFF);
    unsigned short* thw = (unsigned short*)(ws + THW_OFF);
    unsigned short* phw = (unsigned short*)(ws + PHW_OFF);
    unsigned short* gww = (unsigned short*)(ws + GW_OFF);
    unsigned short* oww = (unsigned short*)(ws + OUTW_OFF);
    float* ob = (float*)(ws + OUTB_OFF);
    if (i < 4096) iw[i] = f2bf(((i >> 6) == (i & 63)) ? 1.0f : 0.0f);
    if (i < 16384) {
        float ident = (((i >> 6) & 63) == (i & 63)) ? 1.0f : 0.0f;
        pmw[i] = f2bf(pm_w[i] + ident);
    }
    if (i < 131072) {
        thw[i] = f2bf(th_w[i]);
        phw[i] = f2bf(ph_w[i]);
        gww[i] = f2bf(g_w[i]);
        int o = i >> 8;
        float inv = gamma[o] * rsqrtf(var[o] + 1e-5f);
        oww[i] = f2bf(out_w[i] * inv);
    }
    if (i < 512) {
        float inv = gamma[i] * rsqrtf(var[i] + 1e-5f);
        ob[i] = beta[i] - mean[i] * inv;
    }
}

// Stages ONE K-half (256 channels; this wave's 64) of src into the 32KB frag
// region: rows c = khalf*256 + wid*64 + [0,64) token-mixed by Bm (I or pm_w+I),
// D-tiles stored as MFMA32 frag-array (R7..R9-verified layout, c32 local 0..7).
// NOTE: Bm/bias must correspond to the HEAD of the STAGED CHANNELS,
// head = (khalf*4 + wid) >> 1 — NOT the wave's compute-head (R13 bug).
template<bool WITH_BIAS>
__device__ __forceinline__ void stage_half(const float* __restrict__ src,
                                           const char* __restrict__ Bm,
                                           const float* __restrict__ bias,
                                           char* __restrict__ dst,
                                           int khalf, int wid, int l15, int l4) {
    const int cb0 = khalf * 256 + wid * 64;
    #pragma unroll
    for (int mth = 0; mth < 2; ++mth) {
        f32x4 acc[4][2] = {};
        #pragma unroll
        for (int ks = 0; ks < 2; ++ks) {
            short8 a[4], bb[2];
            #pragma unroll
            for (int ct = 0; ct < 4; ++ct) {
                const float* p = src + (cb0 + ct * 16 + l15) * 64 + ks * 32 + l4 * 8;
                a[ct] = pack8(*(const f32x4*)p, *(const f32x4*)(p + 4));
            }
            #pragma unroll
            for (int mt2 = 0; mt2 < 2; ++mt2)
                bb[mt2] = *(const short8*)(Bm + (mth * 32 + mt2 * 16 + l15) * 128 + ks * 64 + l4 * 16);
            #pragma unroll
            for (int ct = 0; ct < 4; ++ct)
                #pragma unroll
                for (int mt2 = 0; mt2 < 2; ++mt2)
                    acc[ct][mt2] = MFMA32(a[ct], bb[mt2], acc[ct][mt2]);
        }
        #pragma unroll
        for (int ct = 0; ct < 4; ++ct)
            #pragma unroll
            for (int mt2 = 0; mt2 < 2; ++mt2) {
                f32x4 v = acc[ct][mt2];
                if (WITH_BIAS) v += bias[mth * 32 + mt2 * 16 + l15];
                us4 pk;
                pk[0] = f2bf(v[0]); pk[1] = f2bf(v[1]); pk[2] = f2bf(v[2]); pk[3] = f2bf(v[3]);
                const int c32l = wid * 2 + (ct >> 1);
                const int mt = mth * 2 + mt2;
                const int lanep = ((ct & 1) * 2 + (l4 >> 1)) * 16 + l15;
                *(us4*)(dst + (c32l * 4 + mt) * 1024 + lanep * 16 + (l4 & 1) * 8) = pk;
            }
    }
}

// One batch per block, 4 waves, wave = HEAD. R14 = R13 + head-index fix:
// LDS 32KB via K-halved staging + launch_bounds(256,3) (170-reg cap) =>
// 3 blocks/CU = 12 waves/CU (+50% vs R9's 8). R10/R11 proved per-wave ILP
// is compiler-hostage; HW wave arbitration is the remaining lever. Phi/G
// half-0 partials packed to bf16 (ph0/g0) and unpacked as MFMA C-init for
// half 1 (~0.005 absmax; margin 3.7x). Math otherwise = R9.
// rule #20: all reg-array subscripts compile-time.
__global__ __launch_bounds__(256, 3)
void lawin_main(const float* __restrict__ query, const float* __restrict__ context,
                const float* __restrict__ pm_b, const float* __restrict__ th_b,
                const float* __restrict__ ph_b, const float* __restrict__ g_b,
                const char* __restrict__ ws, float* __restrict__ out) {
    __shared__ __align__(16) char FR[32768];

    const char* iw  = ws + IW_OFF;
    const char* pmw = ws + PMW_OFF;
    const char* thw = ws + THW_OFF;
    const char* phw = ws + PHW_OFF;
    const char* gww = ws + GW_OFF;
    const char* oww = ws + OUTW_OFF;
    const float* ob = (const float*)(ws + OUTB_OFF);

    const int b = blockIdx.x;
    const int tid = threadIdx.x;
    const int wid = tid >> 6;          // wave = head (for compute phases)
    const int lane = tid & 63;
    const int l15 = lane & 15;
    const int l4 = lane >> 4;
    const int h = wid;

    const float* qb = query + (size_t)b * 32768;
    const float* cbp = context + (size_t)b * 32768;
    float* outb = out + (size_t)b * 32768;

    // ---------- Theta over two q^T half-stages (thacc f32 across halves) ----------
    short4v thB[4][4];
    {
        f32x4 thacc[4][4] = {};
        #pragma unroll
        for (int khalf = 0; khalf < 2; ++khalf) {
            stage_half<false>(qb, iw, nullptr, FR, khalf, wid, l15, l4);
            __syncthreads();
            #pragma unroll 2
            for (int ks = 0; ks < 8; ++ks) {
                short8 a[4], bb[4];
                #pragma unroll
                for (int td = 0; td < 4; ++td)
                    a[td] = *(const short8*)(thw + (h * 64 + td * 16 + l15) * 1024 + khalf * 512 + ks * 64 + l4 * 16);
                #pragma unroll
                for (int tb = 0; tb < 4; ++tb)
                    bb[tb] = *(const short8*)(FR + (ks * 4 + tb) * 1024 + lane * 16);
                #pragma unroll
                for (int td = 0; td < 4; ++td)
                    #pragma unroll
                    for (int tb = 0; tb < 4; ++tb)
                        thacc[td][tb] = MFMA32(a[td], bb[tb], thacc[td][tb]);
            }
            __syncthreads();   // frag region free for next stage
        }
        #pragma unroll
        for (int td = 0; td < 4; ++td) {
            f32x4 bv = *(const f32x4*)(th_b + h * 64 + td * 16 + l4 * 4);
            #pragma unroll
            for (int tb = 0; tb < 4; ++tb)
                thB[td][tb] = pack4(thacc[td][tb] + bv);
        }
    }

    // head of the channels THIS WAVE stages in ctx half k: (k*4 + wid) >> 1
    const int sh0 = (0 * 4 + wid) >> 1;
    const int sh1 = (1 * 4 + wid) >> 1;

    // ---------- ctx' half 0: Phi0 and G0 partials, packed to bf16 ----------
    short4v ph0[4][4], g0[4][4];
    stage_half<true>(cbp, pmw + sh0 * 8192, pm_b + sh0 * 64, FR, 0, wid, l15, l4);
    __syncthreads();
    {
        f32x4 pacc[4][4] = {};
        #pragma unroll 2
        for (int ks = 0; ks < 8; ++ks) {
            short8 a[4], bb[4];
            #pragma unroll
            for (int td = 0; td < 4; ++td)
                a[td] = *(const short8*)(phw + (h * 64 + td * 16 + l15) * 1024 + ks * 64 + l4 * 16);
            #pragma unroll
            for (int tc = 0; tc < 4; ++tc)
                bb[tc] = *(const short8*)(FR + (ks * 4 + tc) * 1024 + lane * 16);
            #pragma unroll
            for (int td = 0; td < 4; ++td)
                #pragma unroll
                for (int tc = 0; tc < 4; ++tc)
                    pacc[td][tc] = MFMA32(a[td], bb[tc], pacc[td][tc]);
        }
        #pragma unroll
        for (int td = 0; td < 4; ++td)
            #pragma unroll
            for (int tc = 0; tc < 4; ++tc)
                ph0[td][tc] = pack4(pacc[td][tc]);
    }
    {
        f32x4 gacc[4][4] = {};
        #pragma unroll 2
        for (int ks = 0; ks < 8; ++ks) {
            short8 a[4], bb[4];
            #pragma unroll
            for (int tn = 0; tn < 4; ++tn)
                a[tn] = *(const short8*)(FR + (ks * 4 + tn) * 1024 + lane * 16);
            #pragma unroll
            for (int tg = 0; tg < 4; ++tg)
                bb[tg] = *(const short8*)(gww + (h * 64 + tg * 16 + l15) * 1024 + ks * 64 + l4 * 16);
            #pragma unroll
            for (int tn = 0; tn < 4; ++tn)
                #pragma unroll
                for (int tg = 0; tg < 4; ++tg)
                    gacc[tn][tg] = MFMA32(a[tn], bb[tg], gacc[tn][tg]);
        }
        #pragma unroll
        for (int tn = 0; tn < 4; ++tn)
            #pragma unroll
            for (int tg = 0; tg < 4; ++tg)
                g0[tn][tg] = pack4(gacc[tn][tg]);
    }
    __syncthreads();

    // ---------- ctx' half 1 staged; Phi1 -> S -> softmax -> pB ----------
    stage_half<true>(cbp, pmw + sh1 * 8192, pm_b + sh1 * 64, FR, 1, wid, l15, l4);
    __syncthreads();

    short4v pB[4][4];
    {
        f32x4 pacc[4][4];
        #pragma unroll
        for (int td = 0; td < 4; ++td)
            #pragma unroll
            for (int tc = 0; tc < 4; ++tc)
                #pragma unroll
                for (int r = 0; r < 4; ++r)
                    pacc[td][tc][r] = bf2f((unsigned short)ph0[td][tc][r]);
        #pragma unroll 2
        for (int ks = 0; ks < 8; ++ks) {
            short8 a[4], bb[4];
            #pragma unroll
            for (int td = 0; td < 4; ++td)
                a[td] = *(const short8*)(phw + (h * 64 + td * 16 + l15) * 1024 + 512 + ks * 64 + l4 * 16);
            #pragma unroll
            for (int tc = 0; tc < 4; ++tc)
                bb[tc] = *(const short8*)(FR + (ks * 4 + tc) * 1024 + lane * 16);
            #pragma unroll
            for (int td = 0; td < 4; ++td)
                #pragma unroll
                for (int tc = 0; tc < 4; ++tc)
                    pacc[td][tc] = MFMA32(a[td], bb[tc], pacc[td][tc]);
        }
        f32x4 s_acc[4][4] = {};
        #pragma unroll
        for (int td = 0; td < 4; ++td) {
            f32x4 bv = *(const f32x4*)(ph_b + h * 64 + td * 16 + l4 * 4);
            #pragma unroll
            for (int tc = 0; tc < 4; ++tc) {
                short4v phB = pack4(pacc[td][tc] + bv);
                #pragma unroll
                for (int tb = 0; tb < 4; ++tb)
                    s_acc[tc][tb] = mfma16(phB, thB[td][tb], s_acc[tc][tb]);
            }
        }
        // softmax over nc (per-lane 16 values + shfl over l4), scale 1/8
        #pragma unroll
        for (int tb = 0; tb < 4; ++tb) {
            float mx = -1e30f;
            #pragma unroll
            for (int tc = 0; tc < 4; ++tc)
                #pragma unroll
                for (int r = 0; r < 4; ++r) mx = fmaxf(mx, s_acc[tc][tb][r]);
            mx = fmaxf(mx, __shfl_xor(mx, 16));
            mx = fmaxf(mx, __shfl_xor(mx, 32));
            float sum = 0.f;
            #pragma unroll
            for (int tc = 0; tc < 4; ++tc)
                #pragma unroll
                for (int r = 0; r < 4; ++r) {
                    float v = __expf((s_acc[tc][tb][r] - mx) * 0.125f);
                    s_acc[tc][tb][r] = v;
                    sum += v;
                }
            sum += __shfl_xor(sum, 16);
            sum += __shfl_xor(sum, 32);
            float rinv = 1.0f / sum;
            #pragma unroll
            for (int tc = 0; tc < 4; ++tc)
                pB[tc][tb] = pack4(s_acc[tc][tb] * rinv);
        }
    }

    // ---------- G1 (init from g0) -> PV -> y_acc ----------
    f32x4 y_acc[4][4] = {};
    {
        f32x4 gacc[4][4];
        #pragma unroll
        for (int tn = 0; tn < 4; ++tn)
            #pragma unroll
            for (int tg = 0; tg < 4; ++tg)
                #pragma unroll
                for (int r = 0; r < 4; ++r)
                    gacc[tn][tg][r] = bf2f((unsigned short)g0[tn][tg][r]);
        #pragma unroll 2
        for (int ks = 0; ks < 8; ++ks) {
            short8 a[4], bb[4];
            #pragma unroll
            for (int tn = 0; tn < 4; ++tn)
                a[tn] = *(const short8*)(FR + (ks * 4 + tn) * 1024 + lane * 16);
            #pragma unroll
            for (int tg = 0; tg < 4; ++tg)
                bb[tg] = *(const short8*)(gww + (h * 64 + tg * 16 + l15) * 1024 + 512 + ks * 64 + l4 * 16);
            #pragma unroll
            for (int tn = 0; tn < 4; ++tn)
                #pragma unroll
                for (int tg = 0; tg < 4; ++tg)
                    gacc[tn][tg] = MFMA32(a[tn], bb[tg], gacc[tn][tg]);
        }
        #pragma unroll
        for (int tg = 0; tg < 4; ++tg) {
            float gbv = g_b[h * 64 + tg * 16 + l15];
            #pragma unroll
            for (int tn = 0; tn < 4; ++tn) {
                short4v gB = pack4(gacc[tn][tg] + gbv);
                #pragma unroll
                for (int tb = 0; tb < 4; ++tb)
                    y_acc[tb][tg] = mfma16(pB[tn][tb], gB, y_acc[tb][tg]);
            }
        }
    }
    __syncthreads();   // all waves done reading ctx' half-1 frags

    // ---------- Y^T bf16 [64][256] (SW-swizzled) -> FR (32KB) ----------
    #pragma unroll
    for (int tb = 0; tb < 4; ++tb)
        #pragma unroll
        for (int tg = 0; tg < 4; ++tg)
            #pragma unroll
            for (int r = 0; r < 4; ++r) {
                int nq = tb * 16 + l4 * 4 + r;
                int dg = h * 64 + tg * 16 + l15;
                *(unsigned short*)(FR + nq * 512 + ((2 * dg) ^ SW(nq))) = f2bf(y_acc[tb][tg][r]);
            }
    __syncthreads();

    // ---------- T5: out-proj (BN folded) + bias + f32 query residual ----------
    #pragma unroll 1
    for (int och = 0; och < 4; ++och) {    // och only feeds addresses; acc local per iter
        const int ob0 = wid * 128 + och * 32;
        f32x4 acc[4][2] = {};
        #pragma unroll 2
        for (int ks = 0; ks < 8; ++ks) {
            const int kb = ks * 64 + l4 * 16;
            short8 a[4], bb[2];
            #pragma unroll
            for (int tr = 0; tr < 4; ++tr) {
                int tok = tr * 16 + l15;
                a[tr] = *(const short8*)(FR + tok * 512 + (kb ^ SW(tok)));
            }
            #pragma unroll
            for (int oc = 0; oc < 2; ++oc)
                bb[oc] = *(const short8*)(oww + (ob0 + oc * 16 + l15) * 512 + kb);
            #pragma unroll
            for (int tr = 0; tr < 4; ++tr)
                #pragma unroll
                for (int oc = 0; oc < 2; ++oc)
                    acc[tr][oc] = MFMA32(a[tr], bb[oc], acc[tr][oc]);
        }
        #pragma unroll
        for (int oc = 0; oc < 2; ++oc) {
            const int o = ob0 + oc * 16 + l15;
            const float bias = ob[o];
            #pragma unroll
            for (int tr = 0; tr < 4; ++tr) {
                const int tt = tr * 16 + l4 * 4;
                f32x4 qv = *(const f32x4*)(qb + o * 64 + tt);
                f32x4 ov;
                #pragma unroll
                for (int r = 0; r < 4; ++r) ov[r] = acc[tr][oc][r] + bias + qv[r];
                *(f32x4*)(outb + o * 64 + tt) = ov;
            }
        }
    }
}

extern "C" void kernel_launch(void* const* d_in, const int* in_sizes, int n_in,
                              void* d_out, int out_size, void* d_ws, size_t ws_size,
                              hipStream_t stream) {
    const float* query   = (const float*)d_in[0];
    const float* context = (const float*)d_in[1];
    const float* pm_w    = (const float*)d_in[2];
    const float* pm_b    = (const float*)d_in[3];
    const float* g_w     = (const float*)d_in[4];
    const float* g_b     = (const float*)d_in[5];
    const float* th_w    = (const float*)d_in[6];
    const float* th_b    = (const float*)d_in[7];
    const float* ph_w    = (const float*)d_in[8];
    const float* ph_b    = (const float*)d_in[9];
    const float* out_w   = (const float*)d_in[10];
    const float* gamma   = (const float*)d_in[11];
    const float* beta    = (const float*)d_in[12];
    const float* mean    = (const float*)d_in[13];
    const float* var     = (const float*)d_in[14];
    char* ws = (char*)d_ws;
    float* out = (float*)d_out;

    if (ws_size < WS_BYTES) return;

    prep_kernel<<<512, 256, 0, stream>>>(pm_w, g_w, th_w, ph_w, out_w, gamma, beta, mean, var, ws);
    lawin_main<<<NBATCH, 256, 0, stream>>>(query, context, pm_b, th_b, ph_b, g_b, ws, out);
}

// Round 15
// 400.250 us; speedup vs baseline: 1.5039x; 1.4614x over previous
//
#include <hip/hip_runtime.h>

#define NBATCH 2048

typedef __attribute__((ext_vector_type(8))) short short8;
typedef __attribute__((ext_vector_type(4))) short short4v;
typedef __attribute__((ext_vector_type(4))) float f32x4;
typedef __attribute__((ext_vector_type(4))) unsigned short us4;

__device__ __forceinline__ unsigned short f2bf(float f) {
    unsigned int u = __float_as_uint(f);
    u += 0x7FFFu + ((u >> 16) & 1u);
    return (unsigned short)(u >> 16);
}

__device__ __forceinline__ short4v pack4(f32x4 v) {
    short4v r;
    r[0] = (short)f2bf(v[0]); r[1] = (short)f2bf(v[1]);
    r[2] = (short)f2bf(v[2]); r[3] = (short)f2bf(v[3]);
    return r;
}
__device__ __forceinline__ short8 pack8(f32x4 lo, f32x4 hi) {
    short8 r;
    r[0] = (short)f2bf(lo[0]); r[1] = (short)f2bf(lo[1]);
    r[2] = (short)f2bf(lo[2]); r[3] = (short)f2bf(lo[3]);
    r[4] = (short)f2bf(hi[0]); r[5] = (short)f2bf(hi[1]);
    r[6] = (short)f2bf(hi[2]); r[7] = (short)f2bf(hi[3]);
    return r;
}

__device__ __forceinline__ f32x4 mfma16(short4v a, short4v b, f32x4 c) {
#if __has_builtin(__builtin_amdgcn_mfma_f32_16x16x16bf16_1k)
    return __builtin_amdgcn_mfma_f32_16x16x16bf16_1k(a, b, c, 0, 0, 0);
#elif __has_builtin(__builtin_amdgcn_mfma_f32_16x16x16_bf16)
    return __builtin_amdgcn_mfma_f32_16x16x16_bf16(a, b, c, 0, 0, 0);
#else
    asm volatile("v_mfma_f32_16x16x16_bf16 %0, %1, %2, %0" : "+v"(c) : "v"(a), "v"(b));
    return c;
#endif
}
#define MFMA32(a, b, c) __builtin_amdgcn_mfma_f32_16x16x32_bf16(a, b, c, 0, 0, 0)

#define SW(t) ((((t) ^ ((t) >> 3)) & 7) << 4)

// ws layout (bytes)
#define IW_OFF    0u        // I64 bf16 [64][64]
#define PMW_OFF   8192u     // (pm_w + I) bf16 [4][64][64]
#define THW_OFF   40960u    // [256][512] bf16
#define PHW_OFF   303104u   // [256][512] bf16
#define GW_OFF    565248u   // [256][512] bf16
#define OUTW_OFF  827392u   // [512][256] bf16 (BN-scaled)
#define OUTB_OFF  1089536u  // [512] f32 (folded BN bias)
#define WS_BYTES  1091584u

__global__ void prep_kernel(const float* __restrict__ pm_w, const float* __restrict__ g_w,
                            const float* __restrict__ th_w, const float* __restrict__ ph_w,
                            const float* __restrict__ out_w, const float* __restrict__ gamma,
                            const float* __restrict__ beta, const float* __restrict__ mean,
                            const float* __restrict__ var, char* __restrict__ ws) {
    int i = blockIdx.x * 256 + threadIdx.x;
    unsigned short* iw  = (unsigned short*)(ws + IW_OFF);
    unsigned short* pmw = (unsigned short*)(ws + PMW_OFF);
    unsigned short* thw = (unsigned short*)(ws + THW_OFF);
    unsigned short* phw = (unsigned short*)(ws + PHW_OFF);
    unsigned short* gww = (unsigned short*)(ws + GW_OFF);
    unsigned short* oww = (unsigned short*)(ws + OUTW_OFF);
    float* ob = (float*)(ws + OUTB_OFF);
    if (i < 4096) iw[i] = f2bf(((i >> 6) == (i & 63)) ? 1.0f : 0.0f);
    if (i < 16384) {
        float ident = (((i >> 6) & 63) == (i & 63)) ? 1.0f : 0.0f;
        pmw[i] = f2bf(pm_w[i] + ident);
    }
    if (i < 131072) {
        thw[i] = f2bf(th_w[i]);
        phw[i] = f2bf(ph_w[i]);
        gww[i] = f2bf(g_w[i]);
        int o = i >> 8;
        float inv = gamma[o] * rsqrtf(var[o] + 1e-5f);
        oww[i] = f2bf(out_w[i] * inv);
    }
    if (i < 512) {
        float inv = gamma[i] * rsqrtf(var[i] + 1e-5f);
        ob[i] = beta[i] - mean[i] * inv;
    }
}

// Bulk MFMA-transpose stage (verified R7..R9): rows [cw*64, cw*64+64) of src
// (f32 [512][64]) token-mixed by Bm, stored into the 64KB frag-array dst.
template<bool WITH_BIAS>
__device__ __forceinline__ void stage_T(const float* __restrict__ src,
                                        const char* __restrict__ Bm,
                                        const float* __restrict__ bias,
                                        char* __restrict__ dst,
                                        int cw, int l15, int l4) {
    const int cb0 = cw * 64;
    #pragma unroll
    for (int mth = 0; mth < 2; ++mth) {
        f32x4 acc[4][2] = {};
        #pragma unroll
        for (int ks = 0; ks < 2; ++ks) {
            short8 a[4], bb[2];
            #pragma unroll
            for (int ct = 0; ct < 4; ++ct) {
                const float* p = src + (cb0 + ct * 16 + l15) * 64 + ks * 32 + l4 * 8;
                a[ct] = pack8(*(const f32x4*)p, *(const f32x4*)(p + 4));
            }
            #pragma unroll
            for (int mt2 = 0; mt2 < 2; ++mt2)
                bb[mt2] = *(const short8*)(Bm + (mth * 32 + mt2 * 16 + l15) * 128 + ks * 64 + l4 * 16);
            #pragma unroll
            for (int ct = 0; ct < 4; ++ct)
                #pragma unroll
                for (int mt2 = 0; mt2 < 2; ++mt2)
                    acc[ct][mt2] = MFMA32(a[ct], bb[mt2], acc[ct][mt2]);
        }
        #pragma unroll
        for (int ct = 0; ct < 4; ++ct)
            #pragma unroll
            for (int mt2 = 0; mt2 < 2; ++mt2) {
                f32x4 v = acc[ct][mt2];
                if (WITH_BIAS) v += bias[mth * 32 + mt2 * 16 + l15];
                us4 pk;
                pk[0] = f2bf(v[0]); pk[1] = f2bf(v[1]); pk[2] = f2bf(v[2]); pk[3] = f2bf(v[3]);
                const int c32 = cw * 2 + (ct >> 1);
                const int mt = mth * 2 + mt2;
                const int lanep = ((ct & 1) * 2 + (l4 >> 1)) * 16 + l15;
                *(us4*)(dst + (c32 * 4 + mt) * 1024 + lanep * 16 + (l4 & 1) * 8) = pk;
            }
    }
}

// T14 split of stage_T: issue-early loads (named regs) / compute-late.
__device__ __forceinline__ void ctx_gload(const float* __restrict__ src,
                                          f32x4 (&buf)[16], int cw, int l15, int l4) {
    #pragma unroll
    for (int ks = 0; ks < 2; ++ks)
        #pragma unroll
        for (int ct = 0; ct < 4; ++ct) {
            const float* p = src + (cw * 64 + ct * 16 + l15) * 64 + ks * 32 + l4 * 8;
            buf[ks * 8 + ct * 2]     = *(const f32x4*)p;
            buf[ks * 8 + ct * 2 + 1] = *(const f32x4*)(p + 4);
        }
}
__device__ __forceinline__ void ctx_comp(const f32x4 (&buf)[16],
                                         const char* __restrict__ Bm,
                                         const float* __restrict__ bias,
                                         char* __restrict__ dst,
                                         int cw, int l15, int l4) {
    short8 pa[8];
    #pragma unroll
    for (int ks = 0; ks < 2; ++ks)
        #pragma unroll
        for (int ct = 0; ct < 4; ++ct)
            pa[ks * 4 + ct] = pack8(buf[ks * 8 + ct * 2], buf[ks * 8 + ct * 2 + 1]);
    #pragma unroll
    for (int mth = 0; mth < 2; ++mth) {
        f32x4 acc[4][2] = {};
        #pragma unroll
        for (int ks = 0; ks < 2; ++ks) {
            short8 bb[2];
            #pragma unroll
            for (int mt2 = 0; mt2 < 2; ++mt2)
                bb[mt2] = *(const short8*)(Bm + (mth * 32 + mt2 * 16 + l15) * 128 + ks * 64 + l4 * 16);
            #pragma unroll
            for (int ct = 0; ct < 4; ++ct)
                #pragma unroll
                for (int mt2 = 0; mt2 < 2; ++mt2)
                    acc[ct][mt2] = MFMA32(pa[ks * 4 + ct], bb[mt2], acc[ct][mt2]);
        }
        #pragma unroll
        for (int ct = 0; ct < 4; ++ct)
            #pragma unroll
            for (int mt2 = 0; mt2 < 2; ++mt2) {
                f32x4 v = acc[ct][mt2] + bias[mth * 32 + mt2 * 16 + l15];
                us4 pk;
                pk[0] = f2bf(v[0]); pk[1] = f2bf(v[1]); pk[2] = f2bf(v[2]); pk[3] = f2bf(v[3]);
                const int c32 = cw * 2 + (ct >> 1);
                const int mt = mth * 2 + mt2;
                const int lanep = ((ct & 1) * 2 + (l4 >> 1)) * 16 + l15;
                *(us4*)(dst + (c32 * 4 + mt) * 1024 + lanep * 16 + (l4 & 1) * 8) = pk;
            }
    }
}

// One batch per block, 4 waves, wave = HEAD. launch_bounds(256,2): 2
// independent blocks/CU at a 256-reg cap — R9's proven spill-free optimum
// (R13/R14: 3 blocks/CU @170-reg cap spills 567MB; R2..R7: 128-cap worse).
// R15 = R9 + T14 async-STAGE split: first ctx load-group (16 f32x4, 64 regs)
// issued BEFORE the Theta phase so its HBM latency hides under Theta's
// L2/LDS work; pack+MFMA+LDS-write happen after the post-Theta barrier.
// + per-och q-residual prefetch in T5, + bijective XCD swizzle (free).
// LDS 64KB time-multiplexed: q^T frags -> ctx' frags -> Y^T (32KB).
// rule #20: all reg-array subscripts compile-time.
__global__ __launch_bounds__(256, 2)
void lawin_main(const float* __restrict__ query, const float* __restrict__ context,
                const float* __restrict__ pm_b, const float* __restrict__ th_b,
                const float* __restrict__ ph_b, const float* __restrict__ g_b,
                const char* __restrict__ ws, float* __restrict__ out) {
    __shared__ __align__(16) char FR[65536];

    const char* iw  = ws + IW_OFF;
    const char* pmw = ws + PMW_OFF;
    const char* thw = ws + THW_OFF;
    const char* phw = ws + PHW_OFF;
    const char* gww = ws + GW_OFF;
    const char* oww = ws + OUTW_OFF;
    const float* ob = (const float*)(ws + OUTB_OFF);

    // bijective XCD swizzle (2048 % 8 == 0): blocks on one XCD get a
    // contiguous batch range (weight locality only; costless).
    const int b = ((blockIdx.x & 7) << 8) | (blockIdx.x >> 3);
    const int tid = threadIdx.x;
    const int wid = tid >> 6;          // wave = head
    const int lane = tid & 63;
    const int l15 = lane & 15;
    const int l4 = lane >> 4;
    const int h = wid;

    const float* qb = query + (size_t)b * 32768;
    const float* cbp = context + (size_t)b * 32768;
    float* outb = out + (size_t)b * 32768;

    // ---------- T0: q -> q^T frag-array (each wave stages 128 channels) ----------
    stage_T<false>(qb, iw, nullptr, FR, wid * 2, l15, l4);
    stage_T<false>(qb, iw, nullptr, FR, wid * 2 + 1, l15, l4);

    // T14: issue first ctx load-group NOW — HBM latency hides under Theta.
    f32x4 cpre[16];
    ctx_gload(cbp, cpre, wid * 2, l15, l4);
    __syncthreads();

    // ---------- T1: Theta[d][nq] (4 d-tiles x 4 nq-tiles), A=thw(L2), B=q^T(LDS) ----------
    short4v thB[4][4];   // [d16-tile][nq16-tile] as S-mfma B-frags
    {
        f32x4 acc[4][4] = {};
        #pragma unroll 2
        for (int ks = 0; ks < 16; ++ks) {
            short8 a[4], bb[4];
            #pragma unroll
            for (int td = 0; td < 4; ++td)
                a[td] = *(const short8*)(thw + (h * 64 + td * 16 + l15) * 1024 + ks * 64 + l4 * 16);
            #pragma unroll
            for (int tb = 0; tb < 4; ++tb)
                bb[tb] = *(const short8*)(FR + (ks * 4 + tb) * 1024 + lane * 16);
            #pragma unroll
            for (int td = 0; td < 4; ++td)
                #pragma unroll
                for (int tb = 0; tb < 4; ++tb)
                    acc[td][tb] = MFMA32(a[td], bb[tb], acc[td][tb]);
        }
        #pragma unroll
        for (int td = 0; td < 4; ++td) {
            f32x4 bv = *(const f32x4*)(th_b + h * 64 + td * 16 + l4 * 4);
            #pragma unroll
            for (int tb = 0; tb < 4; ++tb)
                thB[td][tb] = pack4(acc[td][tb] + bv);
        }
    }
    __syncthreads();   // all waves done reading q^T

    // ---------- T2: posmix -> ctx' frag-array (group 0 from prefetch) ----------
    ctx_comp(cpre, pmw + h * 8192, pm_b + h * 64, FR, wid * 2, l15, l4);
    stage_T<true>(cbp, pmw + h * 8192, pm_b + h * 64, FR, wid * 2 + 1, l15, l4);
    __syncthreads();

    // ---------- T3: Phi -> S^T -> softmax -> pB ----------
    short4v pB[4][4];    // [nc16-tile][nq16-tile] PV A-frags
    {
        f32x4 s_acc[4][4] = {};   // S^T tiles: row=nc(l4*4+r), col=nq(l15)
        #pragma unroll
        for (int dh = 0; dh < 2; ++dh) {          // FULL unroll: indexes thB
            f32x4 pacc[2][4] = {};   // Phi D[d][nc]: [td2][tc]
            #pragma unroll 2
            for (int ks = 0; ks < 16; ++ks) {
                short8 a[2], bb[4];
                #pragma unroll
                for (int td2 = 0; td2 < 2; ++td2)
                    a[td2] = *(const short8*)(phw + (h * 64 + dh * 32 + td2 * 16 + l15) * 1024 + ks * 64 + l4 * 16);
                #pragma unroll
                for (int tc = 0; tc < 4; ++tc)
                    bb[tc] = *(const short8*)(FR + (ks * 4 + tc) * 1024 + lane * 16);
                #pragma unroll
                for (int td2 = 0; td2 < 2; ++td2)
                    #pragma unroll
                    for (int tc = 0; tc < 4; ++tc)
                        pacc[td2][tc] = MFMA32(a[td2], bb[tc], pacc[td2][tc]);
            }
            #pragma unroll
            for (int td2 = 0; td2 < 2; ++td2) {
                f32x4 bv = *(const f32x4*)(ph_b + h * 64 + dh * 32 + td2 * 16 + l4 * 4);
                #pragma unroll
                for (int tc = 0; tc < 4; ++tc) {
                    short4v phB = pack4(pacc[td2][tc] + bv);
                    #pragma unroll
                    for (int tb = 0; tb < 4; ++tb)
                        s_acc[tc][tb] = mfma16(phB, thB[dh * 2 + td2][tb], s_acc[tc][tb]);
                }
            }
        }
        // softmax over nc (per-lane 16 values + shfl over l4), scale 1/8
        #pragma unroll
        for (int tb = 0; tb < 4; ++tb) {
            float mx = -1e30f;
            #pragma unroll
            for (int tc = 0; tc < 4; ++tc)
                #pragma unroll
                for (int r = 0; r < 4; ++r) mx = fmaxf(mx, s_acc[tc][tb][r]);
            mx = fmaxf(mx, __shfl_xor(mx, 16));
            mx = fmaxf(mx, __shfl_xor(mx, 32));
            float sum = 0.f;
            #pragma unroll
            for (int tc = 0; tc < 4; ++tc)
                #pragma unroll
                for (int r = 0; r < 4; ++r) {
                    float v = __expf((s_acc[tc][tb][r] - mx) * 0.125f);
                    s_acc[tc][tb][r] = v;
                    sum += v;
                }
            sum += __shfl_xor(sum, 16);
            sum += __shfl_xor(sum, 32);
            float rinv = 1.0f / sum;
            #pragma unroll
            for (int tc = 0; tc < 4; ++tc)
                pB[tc][tb] = pack4(s_acc[tc][tb] * rinv);
        }
    }

    // ---------- T4: G^T and PV chain -> y_acc ----------
    f32x4 y_acc[4][4] = {};    // [nq-tile][dg16-tile(local)], row=nq, col=dg
    #pragma unroll
    for (int gh = 0; gh < 2; ++gh) {              // FULL unroll: indexes y_acc
        f32x4 gacc[4][2] = {};   // G D[nc][dg]: [tn][tg]
        #pragma unroll 2
        for (int ks = 0; ks < 16; ++ks) {
            short8 a[4], bb[2];
            #pragma unroll
            for (int tn = 0; tn < 4; ++tn)
                a[tn] = *(const short8*)(FR + (ks * 4 + tn) * 1024 + lane * 16);
            #pragma unroll
            for (int tg = 0; tg < 2; ++tg)
                bb[tg] = *(const short8*)(gww + (h * 64 + gh * 32 + tg * 16 + l15) * 1024 + ks * 64 + l4 * 16);
            #pragma unroll
            for (int tn = 0; tn < 4; ++tn)
                #pragma unroll
                for (int tg = 0; tg < 2; ++tg)
                    gacc[tn][tg] = MFMA32(a[tn], bb[tg], gacc[tn][tg]);
        }
        #pragma unroll
        for (int tg = 0; tg < 2; ++tg) {
            float gbv = g_b[h * 64 + gh * 32 + tg * 16 + l15];
            #pragma unroll
            for (int tn = 0; tn < 4; ++tn) {
                short4v gB = pack4(gacc[tn][tg] + gbv);
                #pragma unroll
                for (int tb = 0; tb < 4; ++tb)
                    y_acc[tb][gh * 2 + tg] = mfma16(pB[tn][tb], gB, y_acc[tb][gh * 2 + tg]);
            }
        }
    }
    __syncthreads();   // all waves done reading ctx' frags

    // ---------- Y^T bf16 [64][256] (SW-swizzled) -> FR[0:32K) ----------
    #pragma unroll
    for (int tb = 0; tb < 4; ++tb)
        #pragma unroll
        for (int tdg = 0; tdg < 4; ++tdg)
            #pragma unroll
            for (int r = 0; r < 4; ++r) {
                int nq = tb * 16 + l4 * 4 + r;
                int dg = h * 64 + tdg * 16 + l15;
                *(unsigned short*)(FR + nq * 512 + ((2 * dg) ^ SW(nq))) = f2bf(y_acc[tb][tdg][r]);
            }
    __syncthreads();

    // ---------- T5: out-proj (BN folded) + bias + f32 query residual ----------
    #pragma unroll 1
    for (int och = 0; och < 4; ++och) {    // och only feeds addresses; acc local per iter
        const int ob0 = wid * 128 + och * 32;
        f32x4 acc[4][2] = {};
        f32x4 qres[8];   // residual prefetch — hides under the MFMA k-loop
        #pragma unroll
        for (int oc = 0; oc < 2; ++oc)
            #pragma unroll
            for (int tr = 0; tr < 4; ++tr)
                qres[oc * 4 + tr] = *(const f32x4*)(qb + (ob0 + oc * 16 + l15) * 64 + tr * 16 + l4 * 4);
        #pragma unroll 2
        for (int ks = 0; ks < 8; ++ks) {
            const int kb = ks * 64 + l4 * 16;
            short8 a[4], bb[2];
            #pragma unroll
            for (int tr = 0; tr < 4; ++tr) {
                int tok = tr * 16 + l15;
                a[tr] = *(const short8*)(FR + tok * 512 + (kb ^ SW(tok)));
            }
            #pragma unroll
            for (int oc = 0; oc < 2; ++oc)
                bb[oc] = *(const short8*)(oww + (ob0 + oc * 16 + l15) * 512 + kb);
            #pragma unroll
            for (int tr = 0; tr < 4; ++tr)
                #pragma unroll
                for (int oc = 0; oc < 2; ++oc)
                    acc[tr][oc] = MFMA32(a[tr], bb[oc], acc[tr][oc]);
        }
        #pragma unroll
        for (int oc = 0; oc < 2; ++oc) {
            const int o = ob0 + oc * 16 + l15;
            const float bias = ob[o];
            #pragma unroll
            for (int tr = 0; tr < 4; ++tr) {
                f32x4 ov;
                #pragma unroll
                for (int r = 0; r < 4; ++r) ov[r] = acc[tr][oc][r] + bias + qres[oc * 4 + tr][r];
                *(f32x4*)(outb + o * 64 + tr * 16 + l4 * 4) = ov;
            }
        }
    }
}

extern "C" void kernel_launch(void* const* d_in, const int* in_sizes, int n_in,
                              void* d_out, int out_size, void* d_ws, size_t ws_size,
                              hipStream_t stream) {
    const float* query   = (const float*)d_in[0];
    const float* context = (const float*)d_in[1];
    const float* pm_w    = (const float*)d_in[2];
    const float* pm_b    = (const float*)d_in[3];
    const float* g_w     = (const float*)d_in[4];
    const float* g_b     = (const float*)d_in[5];
    const float* th_w    = (const float*)d_in[6];
    const float* th_b    = (const float*)d_in[7];
    const float* ph_w    = (const float*)d_in[8];
    const float* ph_b    = (const float*)d_in[9];
    const float* out_w   = (const float*)d_in[10];
    const float* gamma   = (const float*)d_in[11];
    const float* beta    = (const float*)d_in[12];
    const float* mean    = (const float*)d_in[13];
    const float* var     = (const float*)d_in[14];
    char* ws = (char*)d_ws;
    float* out = (float*)d_out;

    if (ws_size < WS_BYTES) return;

    prep_kernel<<<512, 256, 0, stream>>>(pm_w, g_w, th_w, ph_w, out_w, gamma, beta, mean, var, ws);
    lawin_main<<<NBATCH, 256, 0, stream>>>(query, context, pm_b, th_b, ph_b, g_b, ws, out);
}

// Round 17
// 389.329 us; speedup vs baseline: 1.5461x; 1.0281x over previous
//
#include <hip/hip_runtime.h>

#define NBATCH 2048

typedef __attribute__((ext_vector_type(8))) short short8;
typedef __attribute__((ext_vector_type(4))) short short4v;
typedef __attribute__((ext_vector_type(4))) float f32x4;
typedef __attribute__((ext_vector_type(4))) unsigned short us4;

__device__ __forceinline__ unsigned short f2bf(float f) {
    unsigned int u = __float_as_uint(f);
    u += 0x7FFFu + ((u >> 16) & 1u);
    return (unsigned short)(u >> 16);
}

__device__ __forceinline__ short4v pack4(f32x4 v) {
    short4v r;
    r[0] = (short)f2bf(v[0]); r[1] = (short)f2bf(v[1]);
    r[2] = (short)f2bf(v[2]); r[3] = (short)f2bf(v[3]);
    return r;
}
__device__ __forceinline__ short8 pack8(f32x4 lo, f32x4 hi) {
    short8 r;
    r[0] = (short)f2bf(lo[0]); r[1] = (short)f2bf(lo[1]);
    r[2] = (short)f2bf(lo[2]); r[3] = (short)f2bf(lo[3]);
    r[4] = (short)f2bf(hi[0]); r[5] = (short)f2bf(hi[1]);
    r[6] = (short)f2bf(hi[2]); r[7] = (short)f2bf(hi[3]);
    return r;
}

__device__ __forceinline__ f32x4 mfma16(short4v a, short4v b, f32x4 c) {
#if __has_builtin(__builtin_amdgcn_mfma_f32_16x16x16bf16_1k)
    return __builtin_amdgcn_mfma_f32_16x16x16bf16_1k(a, b, c, 0, 0, 0);
#elif __has_builtin(__builtin_amdgcn_mfma_f32_16x16x16_bf16)
    return __builtin_amdgcn_mfma_f32_16x16x16_bf16(a, b, c, 0, 0, 0);
#else
    asm volatile("v_mfma_f32_16x16x16_bf16 %0, %1, %2, %0" : "+v"(c) : "v"(a), "v"(b));
    return c;
#endif
}
#define MFMA32(a, b, c) __builtin_amdgcn_mfma_f32_16x16x32_bf16(a, b, c, 0, 0, 0)

#define SW(t) ((((t) ^ ((t) >> 3)) & 7) << 4)

// ws layout (bytes)
#define IW_OFF    0u        // I64 bf16 [64][64]
#define PMW_OFF   8192u     // (pm_w + I) bf16 [4][64][64]
#define THW_OFF   40960u    // [256][512] bf16
#define PHW_OFF   303104u   // [256][512] bf16
#define GW_OFF    565248u   // [256][512] bf16
#define OUTW_OFF  827392u   // [512][256] bf16 (BN-scaled)
#define OUTB_OFF  1089536u  // [512] f32 (folded BN bias)
#define WS_BYTES  1091584u

__global__ void prep_kernel(const float* __restrict__ pm_w, const float* __restrict__ g_w,
                            const float* __restrict__ th_w, const float* __restrict__ ph_w,
                            const float* __restrict__ out_w, const float* __restrict__ gamma,
                            const float* __restrict__ beta, const float* __restrict__ mean,
                            const float* __restrict__ var, char* __restrict__ ws) {
    int i = blockIdx.x * 256 + threadIdx.x;
    unsigned short* iw  = (unsigned short*)(ws + IW_OFF);
    unsigned short* pmw = (unsigned short*)(ws + PMW_OFF);
    unsigned short* thw = (unsigned short*)(ws + THW_OFF);
    unsigned short* phw = (unsigned short*)(ws + PHW_OFF);
    unsigned short* gww = (unsigned short*)(ws + GW_OFF);
    unsigned short* oww = (unsigned short*)(ws + OUTW_OFF);
    float* ob = (float*)(ws + OUTB_OFF);
    if (i < 4096) iw[i] = f2bf(((i >> 6) == (i & 63)) ? 1.0f : 0.0f);
    if (i < 16384) {
        float ident = (((i >> 6) & 63) == (i & 63)) ? 1.0f : 0.0f;
        pmw[i] = f2bf(pm_w[i] + ident);
    }
    if (i < 131072) {
        thw[i] = f2bf(th_w[i]);
        phw[i] = f2bf(ph_w[i]);
        gww[i] = f2bf(g_w[i]);
        int o = i >> 8;
        float inv = gamma[o] * rsqrtf(var[o] + 1e-5f);
        oww[i] = f2bf(out_w[i] * inv);
    }
    if (i < 512) {
        float inv = gamma[i] * rsqrtf(var[i] + 1e-5f);
        ob[i] = beta[i] - mean[i] * inv;
    }
}

// Bulk MFMA-transpose stage (verified R7..R9): rows [cw*64, cw*64+64) of src
// (f32 [512][64]) token-mixed by Bm, stored into the 64KB frag-array dst.
template<bool WITH_BIAS>
__device__ __forceinline__ void stage_T(const float* __restrict__ src,
                                        const char* __restrict__ Bm,
                                        const float* __restrict__ bias,
                                        char* __restrict__ dst,
                                        int cw, int l15, int l4) {
    const int cb0 = cw * 64;
    #pragma unroll
    for (int mth = 0; mth < 2; ++mth) {
        f32x4 acc[4][2] = {};
        #pragma unroll
        for (int ks = 0; ks < 2; ++ks) {
            short8 a[4], bb[2];
            #pragma unroll
            for (int ct = 0; ct < 4; ++ct) {
                const float* p = src + (cb0 + ct * 16 + l15) * 64 + ks * 32 + l4 * 8;
                a[ct] = pack8(*(const f32x4*)p, *(const f32x4*)(p + 4));
            }
            #pragma unroll
            for (int mt2 = 0; mt2 < 2; ++mt2)
                bb[mt2] = *(const short8*)(Bm + (mth * 32 + mt2 * 16 + l15) * 128 + ks * 64 + l4 * 16);
            #pragma unroll
            for (int ct = 0; ct < 4; ++ct)
                #pragma unroll
                for (int mt2 = 0; mt2 < 2; ++mt2)
                    acc[ct][mt2] = MFMA32(a[ct], bb[mt2], acc[ct][mt2]);
        }
        #pragma unroll
        for (int ct = 0; ct < 4; ++ct)
            #pragma unroll
            for (int mt2 = 0; mt2 < 2; ++mt2) {
                f32x4 v = acc[ct][mt2];
                if (WITH_BIAS) v += bias[mth * 32 + mt2 * 16 + l15];
                us4 pk;
                pk[0] = f2bf(v[0]); pk[1] = f2bf(v[1]); pk[2] = f2bf(v[2]); pk[3] = f2bf(v[3]);
                const int c32 = cw * 2 + (ct >> 1);
                const int mt = mth * 2 + mt2;
                const int lanep = ((ct & 1) * 2 + (l4 >> 1)) * 16 + l15;
                *(us4*)(dst + (c32 * 4 + mt) * 1024 + lanep * 16 + (l4 & 1) * 8) = pk;
            }
    }
}

// One batch per block, 4 waves, wave = HEAD. launch_bounds(256,2):
// 2 waves/EU -> 2 independent blocks/CU at a 256-reg cap. FINAL (champion,
// R9 structure): R10 unroll/setprio null; R11 named-reg MLP null; R12 phase
// merge -55%; R13/R14 3-blocks/CU spills (170-reg cap < ~190 live) -50%;
// R15 T14-prefetch+XCD-swizzle null; R16 cvt_pk asm -> NaN. The structure
// is latency-bound at 2 blocks/CU with compiler-owned load scheduling —
// source-level exhausted; beyond this needs hand-asm pipelining.
// LDS 64KB time-multiplexed: q^T frags -> ctx' frags -> Y^T (32KB).
// rule #20: all reg-array subscripts compile-time.
__global__ __launch_bounds__(256, 2)
void lawin_main(const float* __restrict__ query, const float* __restrict__ context,
                const float* __restrict__ pm_b, const float* __restrict__ th_b,
                const float* __restrict__ ph_b, const float* __restrict__ g_b,
                const char* __restrict__ ws, float* __restrict__ out) {
    __shared__ __align__(16) char FR[65536];

    const char* iw  = ws + IW_OFF;
    const char* pmw = ws + PMW_OFF;
    const char* thw = ws + THW_OFF;
    const char* phw = ws + PHW_OFF;
    const char* gww = ws + GW_OFF;
    const char* oww = ws + OUTW_OFF;
    const float* ob = (const float*)(ws + OUTB_OFF);

    const int b = blockIdx.x;
    const int tid = threadIdx.x;
    const int wid = tid >> 6;          // wave = head
    const int lane = tid & 63;
    const int l15 = lane & 15;
    const int l4 = lane >> 4;
    const int h = wid;

    const float* qb = query + (size_t)b * 32768;
    const float* cbp = context + (size_t)b * 32768;
    float* outb = out + (size_t)b * 32768;

    // ---------- T0: q -> q^T frag-array (each wave stages 128 channels) ----------
    stage_T<false>(qb, iw, nullptr, FR, wid * 2, l15, l4);
    stage_T<false>(qb, iw, nullptr, FR, wid * 2 + 1, l15, l4);
    __syncthreads();

    // ---------- T1: Theta[d][nq] (4 d-tiles x 4 nq-tiles), A=thw(L2), B=q^T(LDS) ----------
    short4v thB[4][4];   // [d16-tile][nq16-tile] as S-mfma B-frags
    {
        f32x4 acc[4][4] = {};
        #pragma unroll 2
        for (int ks = 0; ks < 16; ++ks) {
            short8 a[4], bb[4];
            #pragma unroll
            for (int td = 0; td < 4; ++td)
                a[td] = *(const short8*)(thw + (h * 64 + td * 16 + l15) * 1024 + ks * 64 + l4 * 16);
            #pragma unroll
            for (int tb = 0; tb < 4; ++tb)
                bb[tb] = *(const short8*)(FR + (ks * 4 + tb) * 1024 + lane * 16);
            #pragma unroll
            for (int td = 0; td < 4; ++td)
                #pragma unroll
                for (int tb = 0; tb < 4; ++tb)
                    acc[td][tb] = MFMA32(a[td], bb[tb], acc[td][tb]);
        }
        #pragma unroll
        for (int td = 0; td < 4; ++td) {
            f32x4 bv = *(const f32x4*)(th_b + h * 64 + td * 16 + l4 * 4);
            #pragma unroll
            for (int tb = 0; tb < 4; ++tb)
                thB[td][tb] = pack4(acc[td][tb] + bv);
        }
    }
    __syncthreads();   // all waves done reading q^T

    // ---------- T2: posmix (residual folded into W+I) -> ctx' frag-array ----------
    stage_T<true>(cbp, pmw + h * 8192, pm_b + h * 64, FR, wid * 2, l15, l4);
    stage_T<true>(cbp, pmw + h * 8192, pm_b + h * 64, FR, wid * 2 + 1, l15, l4);
    __syncthreads();

    // ---------- T3: Phi -> S^T -> softmax -> pB ----------
    short4v pB[4][4];    // [nc16-tile][nq16-tile] PV A-frags
    {
        f32x4 s_acc[4][4] = {};   // S^T tiles: row=nc(l4*4+r), col=nq(l15)
        #pragma unroll
        for (int dh = 0; dh < 2; ++dh) {          // FULL unroll: indexes thB
            f32x4 pacc[2][4] = {};   // Phi D[d][nc]: [td2][tc]
            #pragma unroll 2
            for (int ks = 0; ks < 16; ++ks) {
                short8 a[2], bb[4];
                #pragma unroll
                for (int td2 = 0; td2 < 2; ++td2)
                    a[td2] = *(const short8*)(phw + (h * 64 + dh * 32 + td2 * 16 + l15) * 1024 + ks * 64 + l4 * 16);
                #pragma unroll
                for (int tc = 0; tc < 4; ++tc)
                    bb[tc] = *(const short8*)(FR + (ks * 4 + tc) * 1024 + lane * 16);
                #pragma unroll
                for (int td2 = 0; td2 < 2; ++td2)
                    #pragma unroll
                    for (int tc = 0; tc < 4; ++tc)
                        pacc[td2][tc] = MFMA32(a[td2], bb[tc], pacc[td2][tc]);
            }
            #pragma unroll
            for (int td2 = 0; td2 < 2; ++td2) {
                f32x4 bv = *(const f32x4*)(ph_b + h * 64 + dh * 32 + td2 * 16 + l4 * 4);
                #pragma unroll
                for (int tc = 0; tc < 4; ++tc) {
                    short4v phB = pack4(pacc[td2][tc] + bv);
                    #pragma unroll
                    for (int tb = 0; tb < 4; ++tb)
                        s_acc[tc][tb] = mfma16(phB, thB[dh * 2 + td2][tb], s_acc[tc][tb]);
                }
            }
        }
        // softmax over nc (per-lane 16 values + shfl over l4), scale 1/8
        #pragma unroll
        for (int tb = 0; tb < 4; ++tb) {
            float mx = -1e30f;
            #pragma unroll
            for (int tc = 0; tc < 4; ++tc)
                #pragma unroll
                for (int r = 0; r < 4; ++r) mx = fmaxf(mx, s_acc[tc][tb][r]);
            mx = fmaxf(mx, __shfl_xor(mx, 16));
            mx = fmaxf(mx, __shfl_xor(mx, 32));
            float sum = 0.f;
            #pragma unroll
            for (int tc = 0; tc < 4; ++tc)
                #pragma unroll
                for (int r = 0; r < 4; ++r) {
                    float v = __expf((s_acc[tc][tb][r] - mx) * 0.125f);
                    s_acc[tc][tb][r] = v;
                    sum += v;
                }
            sum += __shfl_xor(sum, 16);
            sum += __shfl_xor(sum, 32);
            float rinv = 1.0f / sum;
            #pragma unroll
            for (int tc = 0; tc < 4; ++tc)
                pB[tc][tb] = pack4(s_acc[tc][tb] * rinv);
        }
    }

    // ---------- T4: G^T and PV chain -> y_acc ----------
    f32x4 y_acc[4][4] = {};    // [nq-tile][dg16-tile(local)], row=nq, col=dg
    #pragma unroll
    for (int gh = 0; gh < 2; ++gh) {              // FULL unroll: indexes y_acc
        f32x4 gacc[4][2] = {};   // G D[nc][dg]: [tn][tg]
        #pragma unroll 2
        for (int ks = 0; ks < 16; ++ks) {
            short8 a[4], bb[2];
            #pragma unroll
            for (int tn = 0; tn < 4; ++tn)
                a[tn] = *(const short8*)(FR + (ks * 4 + tn) * 1024 + lane * 16);
            #pragma unroll
            for (int tg = 0; tg < 2; ++tg)
                bb[tg] = *(const short8*)(gww + (h * 64 + gh * 32 + tg * 16 + l15) * 1024 + ks * 64 + l4 * 16);
            #pragma unroll
            for (int tn = 0; tn < 4; ++tn)
                #pragma unroll
                for (int tg = 0; tg < 2; ++tg)
                    gacc[tn][tg] = MFMA32(a[tn], bb[tg], gacc[tn][tg]);
        }
        #pragma unroll
        for (int tg = 0; tg < 2; ++tg) {
            float gbv = g_b[h * 64 + gh * 32 + tg * 16 + l15];
            #pragma unroll
            for (int tn = 0; tn < 4; ++tn) {
                short4v gB = pack4(gacc[tn][tg] + gbv);
                #pragma unroll
                for (int tb = 0; tb < 4; ++tb)
                    y_acc[tb][gh * 2 + tg] = mfma16(pB[tn][tb], gB, y_acc[tb][gh * 2 + tg]);
            }
        }
    }
    __syncthreads();   // all waves done reading ctx' frags

    // ---------- Y^T bf16 [64][256] (SW-swizzled) -> FR[0:32K) ----------
    #pragma unroll
    for (int tb = 0; tb < 4; ++tb)
        #pragma unroll
        for (int tdg = 0; tdg < 4; ++tdg)
            #pragma unroll
            for (int r = 0; r < 4; ++r) {
                int nq = tb * 16 + l4 * 4 + r;
                int dg = h * 64 + tdg * 16 + l15;
                *(unsigned short*)(FR + nq * 512 + ((2 * dg) ^ SW(nq))) = f2bf(y_acc[tb][tdg][r]);
            }
    __syncthreads();

    // ---------- T5: out-proj (BN folded) + bias + f32 query residual ----------
    #pragma unroll 1
    for (int och = 0; och < 4; ++och) {    // och only feeds addresses; acc local per iter
        const int ob0 = wid * 128 + och * 32;
        f32x4 acc[4][2] = {};
        #pragma unroll 2
        for (int ks = 0; ks < 8; ++ks) {
            const int kb = ks * 64 + l4 * 16;
            short8 a[4], bb[2];
            #pragma unroll
            for (int tr = 0; tr < 4; ++tr) {
                int tok = tr * 16 + l15;
                a[tr] = *(const short8*)(FR + tok * 512 + (kb ^ SW(tok)));
            }
            #pragma unroll
            for (int oc = 0; oc < 2; ++oc)
                bb[oc] = *(const short8*)(oww + (ob0 + oc * 16 + l15) * 512 + kb);
            #pragma unroll
            for (int tr = 0; tr < 4; ++tr)
                #pragma unroll
                for (int oc = 0; oc < 2; ++oc)
                    acc[tr][oc] = MFMA32(a[tr], bb[oc], acc[tr][oc]);
        }
        #pragma unroll
        for (int oc = 0; oc < 2; ++oc) {
            const int o = ob0 + oc * 16 + l15;
            const float bias = ob[o];
            #pragma unroll
            for (int tr = 0; tr < 4; ++tr) {
                const int tt = tr * 16 + l4 * 4;
                f32x4 qv = *(const f32x4*)(qb + o * 64 + tt);
                f32x4 ov;
                #pragma unroll
                for (int r = 0; r < 4; ++r) ov[r] = acc[tr][oc][r] + bias + qv[r];
                *(f32x4*)(outb + o * 64 + tt) = ov;
            }
        }
    }
}

extern "C" void kernel_launch(void* const* d_in, const int* in_sizes, int n_in,
                              void* d_out, int out_size, void* d_ws, size_t ws_size,
                              hipStream_t stream) {
    const float* query   = (const float*)d_in[0];
    const float* context = (const float*)d_in[1];
    const float* pm_w    = (const float*)d_in[2];
    const float* pm_b    = (const float*)d_in[3];
    const float* g_w     = (const float*)d_in[4];
    const float* g_b     = (const float*)d_in[5];
    const float* th_w    = (const float*)d_in[6];
    const float* th_b    = (const float*)d_in[7];
    const float* ph_w    = (const float*)d_in[8];
    const float* ph_b    = (const float*)d_in[9];
    const float* out_w   = (const float*)d_in[10];
    const float* gamma   = (const float*)d_in[11];
    const float* beta    = (const float*)d_in[12];
    const float* mean    = (const float*)d_in[13];
    const float* var     = (const float*)d_in[14];
    char* ws = (char*)d_ws;
    float* out = (float*)d_out;

    if (ws_size < WS_BYTES) return;

    prep_kernel<<<512, 256, 0, stream>>>(pm_w, g_w, th_w, ph_w, out_w, gamma, beta, mean, var, ws);
    lawin_main<<<NBATCH, 256, 0, stream>>>(query, context, pm_b, th_b, ph_b, g_b, ws, out);
}